// Round 1
// baseline (716.774 us; speedup 1.0000x reference)
//
#include <hip/hip_runtime.h>
#include <math.h>

// Problem constants
#define B_  2
#define N_  1024
#define DIM_ 768
#define H_  8
#define DH_ 64
#define PD_ 4
// derived
#define NPROJ 1824            // 3*512 + 3*96
#define BH_ (B_*H_)           // 16

// ws layout (float offsets)
#define OFF_QS   0u
#define OFF_KS   (OFF_QS + (size_t)BH_*N_*DH_)      // 1048576
#define OFF_VS   (OFF_KS + (size_t)BH_*N_*DH_)
#define OFF_RS   (OFF_VS + (size_t)BH_*N_*DH_)
#define OFF_QP   (OFF_RS + (size_t)BH_*N_*DH_)      // + 196608 each below
#define OFF_KP   (OFF_QP + (size_t)BH_*N_*12)
#define OFF_VP   (OFF_KP + (size_t)BH_*N_*12)
#define OFF_RP   (OFF_VP + (size_t)BH_*N_*12)
#define OFF_Q2   (OFF_RP + (size_t)BH_*N_*12)
#define OFF_K2   (OFF_Q2 + (size_t)BH_*N_)
#define OFF_PRAW (OFF_K2 + (size_t)BH_*N_)          // B*N*288 = 589824

__device__ __forceinline__ float dot4(float4 a, float4 b) {
    return a.x*b.x + a.y*b.y + a.z*b.z + a.w*b.w;
}

// ---------------------------------------------------------------------------
// K1: projections. grid = (B*N/8), block = 256.  8 rows per block.
// ---------------------------------------------------------------------------
__global__ __launch_bounds__(256) void k_proj(
    const float* __restrict__ x,
    const float* __restrict__ Wsq, const float* __restrict__ Wsk,
    const float* __restrict__ Wsv, const float* __restrict__ Wpq,
    const float* __restrict__ Wpk, const float* __restrict__ Wpv,
    float* __restrict__ ws)
{
    __shared__ float sX[8][DIM_];
    const int tid = threadIdx.x;
    const int row0 = blockIdx.x * 8;

    for (int i = tid; i < 8*DIM_; i += 256) {
        sX[i / DIM_][i % DIM_] = x[(size_t)row0*DIM_ + i];
    }
    __syncthreads();

    float* ws_qs = ws + OFF_QS;
    float* ws_ks = ws + OFF_KS;
    float* ws_vs = ws + OFF_VS;
    float* ws_praw = ws + OFF_PRAW;

    for (int o = tid; o < NPROJ; o += 256) {
        const float* wrow;
        if (o < 1536) {
            int wi = o >> 9;
            const float* W = (wi == 0) ? Wsq : (wi == 1) ? Wsk : Wsv;
            wrow = W + (size_t)(o & 511) * DIM_;
        } else {
            int oo = o - 1536;
            int wi = oo / 96;
            const float* W = (wi == 0) ? Wpq : (wi == 1) ? Wpk : Wpv;
            wrow = W + (size_t)(oo % 96) * DIM_;
        }
        float acc[8];
        #pragma unroll
        for (int r = 0; r < 8; ++r) acc[r] = 0.f;

        for (int d = 0; d < DIM_; d += 4) {
            float4 w = *reinterpret_cast<const float4*>(wrow + d);
            #pragma unroll
            for (int r = 0; r < 8; ++r) {
                acc[r] += w.x * sX[r][d] + w.y * sX[r][d+1]
                        + w.z * sX[r][d+2] + w.w * sX[r][d+3];
            }
        }
        #pragma unroll
        for (int r = 0; r < 8; ++r) {
            int row = row0 + r;
            int b = row >> 10, n = row & (N_-1);
            if (o < 1536) {
                int wi = o >> 9;
                int h = (o >> 6) & 7, c = o & 63;
                float* dst = (wi == 0) ? ws_qs : (wi == 1) ? ws_ks : ws_vs;
                dst[(((size_t)(b*H_ + h))*N_ + n)*DH_ + c] = acc[r];
            } else {
                ws_praw[(size_t)row*288 + (o - 1536)] = acc[r];
            }
        }
    }
}

// ---------------------------------------------------------------------------
// K2: rotate points + q2/k2. grid = B*N, block = 128.
// ---------------------------------------------------------------------------
__global__ __launch_bounds__(128) void k_rot(
    const float* __restrict__ rotations,
    const float* __restrict__ translations,
    float* __restrict__ ws)
{
    __shared__ float R[9], T[3];
    __shared__ float partial[2][8][4];
    const int tid = threadIdx.x;
    const int row = blockIdx.x;
    const int b = row >> 10, n = row & (N_-1);

    if (tid < 9)  R[tid] = rotations[(size_t)row*9 + tid];
    if (tid >= 9 && tid < 12) T[tid-9] = translations[(size_t)row*3 + (tid-9)];
    __syncthreads();

    if (tid < 96) {
        int which = tid / 32;      // 0=q,1=k,2=v
        int idx = tid & 31;
        int h = idx >> 2, pd = idx & 3;
        const float* p = ws + OFF_PRAW + (size_t)row*288 + which*96 + h*12 + pd*3;
        float px = p[0], py = p[1], pz = p[2];
        float c0 = R[0]*px + R[1]*py + R[2]*pz + T[0];
        float c1 = R[3]*px + R[4]*py + R[5]*pz + T[1];
        float c2 = R[6]*px + R[7]*py + R[8]*pz + T[2];
        float* dst = ws + (which == 0 ? OFF_QP : which == 1 ? OFF_KP : OFF_VP)
                   + (((size_t)(b*H_ + h))*N_ + n)*12 + pd*3;
        dst[0] = c0; dst[1] = c1; dst[2] = c2;
        if (which < 2) partial[which][h][pd] = c0*c0 + c1*c1 + c2*c2;
    }
    __syncthreads();
    if (tid < 16) {
        int which = tid >> 3, h = tid & 7;
        float s = partial[which][h][0] + partial[which][h][1]
                + partial[which][h][2] + partial[which][h][3];
        float* dst = ws + (which == 0 ? OFF_Q2 : OFF_K2);
        dst[(size_t)(b*H_ + h)*N_ + n] = s;
    }
}

// ---------------------------------------------------------------------------
// K3: attention. grid = B*H*(N/32) = 512, block = 256.
// thread identity: q = tid&31 (query in tile), g = tid>>5 (dim group 0..7)
// ---------------------------------------------------------------------------
__global__ __launch_bounds__(256) void k_attn(
    const float* __restrict__ point_weights,
    float* __restrict__ ws)
{
    __shared__ float sKs[64*64];
    __shared__ float sVs[64*64];
    __shared__ float sKp[64*12];
    __shared__ float sVp[64*12];
    __shared__ float sK2[64];
    __shared__ float sP[32*65];
    __shared__ float sPmax[32*9];
    __shared__ float sPsum[32*9];

    const int tid = threadIdx.x;
    const int q  = tid & 31;
    const int g  = tid >> 5;
    const int qt = blockIdx.x & 31;
    const int bh = blockIdx.x >> 5;
    const int h  = bh & 7;
    const int q0 = qt * 32;

    const float scalar_scale = 0.08838834764831845f;   // (2*64)^-0.5
    const float point_scale  = 1.0f / 6.0f;            // (2*4*4.5)^-0.5
    const float pw = log1pf(expf(point_weights[h]));
    const float coef = 0.5f * pw * point_scale;

    const float* ws_qs = ws + OFF_QS + (size_t)bh*N_*DH_;
    const float* ws_ks = ws + OFF_KS + (size_t)bh*N_*DH_;
    const float* ws_vs = ws + OFF_VS + (size_t)bh*N_*DH_;
    const float* ws_qp = ws + OFF_QP + (size_t)bh*N_*12;
    const float* ws_kp = ws + OFF_KP + (size_t)bh*N_*12;
    const float* ws_vp = ws + OFF_VP + (size_t)bh*N_*12;
    const float* ws_q2 = ws + OFF_Q2 + (size_t)bh*N_;
    const float* ws_k2 = ws + OFF_K2 + (size_t)bh*N_;
    float* ws_rs = ws + OFF_RS + (size_t)bh*N_*DH_;
    float* ws_rp = ws + OFF_RP + (size_t)bh*N_*12;

    // per-thread query row in registers (reused across all 16 key tiles)
    float4 qr[16];
    {
        const float4* src = reinterpret_cast<const float4*>(ws_qs + (size_t)(q0 + q)*DH_);
        #pragma unroll
        for (int c = 0; c < 16; ++c) qr[c] = src[c];
    }
    float qp_r[12];
    #pragma unroll
    for (int d = 0; d < 12; ++d) qp_r[d] = ws_qp[(size_t)(q0 + q)*12 + d];
    const float q2v = ws_q2[q0 + q];

    float m = -1e30f, l = 0.f;
    float accs[8];
    #pragma unroll
    for (int k = 0; k < 8; ++k) accs[k] = 0.f;
    float accp0 = 0.f, accp1 = 0.f;

    for (int jt = 0; jt < N_/64; ++jt) {
        const int j0 = jt * 64;
        __syncthreads();   // protect staging + sP against previous iteration
        {
            const float4* src = reinterpret_cast<const float4*>(ws_ks + (size_t)j0*DH_);
            float4* dst = reinterpret_cast<float4*>(sKs);
            for (int i = tid; i < 1024; i += 256) dst[i] = src[i];
            src = reinterpret_cast<const float4*>(ws_vs + (size_t)j0*DH_);
            dst = reinterpret_cast<float4*>(sVs);
            for (int i = tid; i < 1024; i += 256) dst[i] = src[i];
            if (tid < 192) {
                reinterpret_cast<float4*>(sKp)[tid] =
                    reinterpret_cast<const float4*>(ws_kp + (size_t)j0*12)[tid];
                reinterpret_cast<float4*>(sVp)[tid] =
                    reinterpret_cast<const float4*>(ws_vp + (size_t)j0*12)[tid];
            }
            if (tid < 64) sK2[tid] = ws_k2[j0 + tid];
        }
        __syncthreads();

        // S tile: this thread covers j = g*8 .. g*8+7
        float s[8];
        float lmax = -1e30f;
        #pragma unroll
        for (int jj = 0; jj < 8; ++jj) {
            int j = g*8 + jj;
            const float4* kr = reinterpret_cast<const float4*>(&sKs[j*64]);
            float dot = 0.f;
            #pragma unroll
            for (int c = 0; c < 16; ++c) dot += dot4(qr[c], kr[c]);
            float qk = 0.f;
            #pragma unroll
            for (int d = 0; d < 12; ++d) qk += qp_r[d] * sKp[j*12 + d];
            float sv = dot*scalar_scale + 2.f*coef*qk - coef*(q2v + sK2[j]);
            s[jj] = sv;
            lmax = fmaxf(lmax, sv);
        }
        sPmax[q*9 + g] = lmax;
        __syncthreads();

        float mnew = m;
        #pragma unroll
        for (int gg = 0; gg < 8; ++gg) mnew = fmaxf(mnew, sPmax[q*9 + gg]);
        const float scale = __expf(m - mnew);
        float psum = 0.f;
        #pragma unroll
        for (int jj = 0; jj < 8; ++jj) {
            float p = __expf(s[jj] - mnew);
            sP[q*65 + g*8 + jj] = p;
            psum += p;
        }
        sPsum[q*9 + g] = psum;
        __syncthreads();

        float tots = 0.f;
        #pragma unroll
        for (int gg = 0; gg < 8; ++gg) tots += sPsum[q*9 + gg];
        l = l*scale + tots;
        m = mnew;
        #pragma unroll
        for (int k = 0; k < 8; ++k) accs[k] *= scale;
        accp0 *= scale; accp1 *= scale;

        for (int j = 0; j < 64; ++j) {
            float p = sP[q*65 + j];
            const float4* vr = reinterpret_cast<const float4*>(&sVs[j*64 + g*8]);
            float4 v0 = vr[0], v1 = vr[1];
            accs[0] += p*v0.x; accs[1] += p*v0.y; accs[2] += p*v0.z; accs[3] += p*v0.w;
            accs[4] += p*v1.x; accs[5] += p*v1.y; accs[6] += p*v1.z; accs[7] += p*v1.w;
            if (g < 6) {
                accp0 += p * sVp[j*12 + 2*g];
                accp1 += p * sVp[j*12 + 2*g + 1];
            }
        }
    }

    const float inv = 1.0f / l;
    float* dsts = ws_rs + (size_t)(q0 + q)*DH_ + g*8;
    #pragma unroll
    for (int k = 0; k < 8; ++k) dsts[k] = accs[k] * inv;
    if (g < 6) {
        float* dstp = ws_rp + (size_t)(q0 + q)*12 + 2*g;
        dstp[0] = accp0 * inv;
        dstp[1] = accp1 * inv;
    }
}

// ---------------------------------------------------------------------------
// K4: finalize (inverse rotation, norms, concat) + output GEMM.
// grid = B*N/8 = 256, block = 256.
// ---------------------------------------------------------------------------
__global__ __launch_bounds__(256) void k_fin(
    const float* __restrict__ rotations,
    const float* __restrict__ translations,
    const float* __restrict__ Wout,
    const float* __restrict__ bout,
    const float* __restrict__ ws,
    float* __restrict__ out)
{
    __shared__ float sF[8][640];
    const int tid = threadIdx.x;
    const int row0 = blockIdx.x * 8;
    const int b = row0 >> 10;
    const float* ws_rs = ws + OFF_RS;
    const float* ws_rp = ws + OFF_RP;

    // scalar part: rs -> sF[r][0:512]  (layout h*64+c)
    for (int i = tid; i < 8*512; i += 256) {
        int r = i >> 9, f = i & 511;
        int h = f >> 6, c = f & 63;
        int n = (row0 & (N_-1)) + r;
        sF[r][f] = ws_rs[(((size_t)(b*H_ + h))*N_ + n)*DH_ + c];
    }
    // point part: one (r,h,pd) per thread
    {
        int r = tid >> 5;
        int idx = tid & 31;
        int h = idx >> 2, pd = idx & 3;
        int row = row0 + r;
        int n = row & (N_-1);
        const float* rp = ws_rp + (((size_t)(b*H_ + h))*N_ + n)*12 + pd*3;
        const float* R = rotations + (size_t)row*9;
        const float* T = translations + (size_t)row*3;
        float d0 = rp[0] - T[0], d1 = rp[1] - T[1], d2 = rp[2] - T[2];
        float l0 = R[0]*d0 + R[3]*d1 + R[6]*d2;   // R^T (rp - t)
        float l1 = R[1]*d0 + R[4]*d1 + R[7]*d2;
        float l2 = R[2]*d0 + R[5]*d1 + R[8]*d2;
        sF[r][512 + h*12 + pd*3 + 0] = l0;
        sF[r][512 + h*12 + pd*3 + 1] = l1;
        sF[r][512 + h*12 + pd*3 + 2] = l2;
        sF[r][608 + h*4 + pd] = sqrtf(l0*l0 + l1*l1 + l2*l2 + 1e-8f);
    }
    __syncthreads();

    // output GEMM: out[row][o] = sF[r][:] . Wout[o][:] + bout[o]
    for (int o = tid; o < DIM_; o += 256) {
        float acc[8];
        #pragma unroll
        for (int r = 0; r < 8; ++r) acc[r] = 0.f;
        const float4* wr = reinterpret_cast<const float4*>(Wout + (size_t)o*640);
        for (int f4 = 0; f4 < 160; ++f4) {
            float4 w = wr[f4];
            #pragma unroll
            for (int r = 0; r < 8; ++r) {
                const float4 fv = reinterpret_cast<const float4*>(sF[r])[f4];
                acc[r] += dot4(w, fv);
            }
        }
        float bo = bout[o];
        #pragma unroll
        for (int r = 0; r < 8; ++r) {
            out[(size_t)(row0 + r)*DIM_ + o] = acc[r] + bo;
        }
    }
}

// ---------------------------------------------------------------------------
extern "C" void kernel_launch(void* const* d_in, const int* in_sizes, int n_in,
                              void* d_out, int out_size, void* d_ws, size_t ws_size,
                              hipStream_t stream) {
    const float* x            = (const float*)d_in[0];
    const float* rotations    = (const float*)d_in[1];
    const float* translations = (const float*)d_in[2];
    const float* Wsq          = (const float*)d_in[3];
    const float* Wsk          = (const float*)d_in[4];
    const float* Wsv          = (const float*)d_in[5];
    const float* Wpq          = (const float*)d_in[6];
    const float* Wpk          = (const float*)d_in[7];
    const float* Wpv          = (const float*)d_in[8];
    const float* pweights     = (const float*)d_in[9];
    const float* Wout         = (const float*)d_in[10];
    const float* bout         = (const float*)d_in[11];
    float* out = (float*)d_out;
    float* ws  = (float*)d_ws;

    k_proj<<<B_*N_/8, 256, 0, stream>>>(x, Wsq, Wsk, Wsv, Wpq, Wpk, Wpv, ws);
    k_rot<<<B_*N_, 128, 0, stream>>>(rotations, translations, ws);
    k_attn<<<BH_*(N_/32), 256, 0, stream>>>(pweights, ws);
    k_fin<<<B_*N_/8, 256, 0, stream>>>(rotations, translations, Wout, bout, ws, out);
}

// Round 2
// 367.745 us; speedup vs baseline: 1.9491x; 1.9491x over previous
//
#include <hip/hip_runtime.h>
#include <hip/hip_bf16.h>
#include <math.h>

// Problem constants
#define B_  2
#define N_  1024
#define DIM_ 768
#define H_  8
#define DH_ 64
#define PD_ 4
#define NPROJ 1824            // 3*512 + 3*96
#define NPAD  1920            // padded to 15*128
#define BH_ (B_*H_)           // 16

// ws layout (float offsets)
#define OFF_QS   0u
#define OFF_KS   (OFF_QS + (size_t)BH_*N_*DH_)
#define OFF_VS   (OFF_KS + (size_t)BH_*N_*DH_)
#define OFF_RS   (OFF_VS + (size_t)BH_*N_*DH_)
#define OFF_QP   (OFF_RS + (size_t)BH_*N_*DH_)
#define OFF_KP   (OFF_QP + (size_t)BH_*N_*12)
#define OFF_VP   (OFF_KP + (size_t)BH_*N_*12)
#define OFF_RP   (OFF_VP + (size_t)BH_*N_*12)
#define OFF_Q2   (OFF_RP + (size_t)BH_*N_*12)
#define OFF_K2   (OFF_Q2 + (size_t)BH_*N_)
#define OFF_PRAW (OFF_K2 + (size_t)BH_*N_)          // B*N*288

// bf16 scratch overlapping regions not yet written at GEMM time:
// xb in RS region (786432 float slots needed; RS has 1048576)
// wb right after xb (737280 float slots) -> overlaps QP/KP/VP (written later)
#define OFF_XB   OFF_RS
#define OFF_WB   (OFF_RS + (size_t)(B_*N_*DIM_)/2)

typedef __attribute__((ext_vector_type(8))) short bf16x8;
typedef __attribute__((ext_vector_type(4))) float f32x4;

__device__ __forceinline__ float dot4(float4 a, float4 b) {
    return a.x*b.x + a.y*b.y + a.z*b.z + a.w*b.w;
}

__device__ __forceinline__ unsigned short f2bf(float f) {
    __hip_bfloat16 h = __float2bfloat16(f);
    return *reinterpret_cast<unsigned short*>(&h);
}

// ---------------------------------------------------------------------------
// convert x -> bf16
// ---------------------------------------------------------------------------
__global__ __launch_bounds__(256) void k_cvt_x(
    const float* __restrict__ x, unsigned short* __restrict__ xb)
{
    int i = blockIdx.x * 256 + threadIdx.x;      // one float4 per thread
    if (i >= (B_*N_*DIM_)/4) return;
    float4 v = reinterpret_cast<const float4*>(x)[i];
    ushort4 o;
    o.x = f2bf(v.x); o.y = f2bf(v.y); o.z = f2bf(v.z); o.w = f2bf(v.w);
    reinterpret_cast<ushort4*>(xb)[i] = o;
}

// ---------------------------------------------------------------------------
// pack 6 weight mats into wb[1920][768] bf16 (rows >= 1824 zeroed)
// ---------------------------------------------------------------------------
__global__ __launch_bounds__(256) void k_cvt_w(
    const float* __restrict__ Wsq, const float* __restrict__ Wsk,
    const float* __restrict__ Wsv, const float* __restrict__ Wpq,
    const float* __restrict__ Wpk, const float* __restrict__ Wpv,
    unsigned short* __restrict__ wb)
{
    int i = blockIdx.x * 256 + threadIdx.x;      // one float4 per thread
    if (i >= (NPAD*DIM_)/4) return;
    int row = i / (DIM_/4);
    int c4  = i % (DIM_/4);
    ushort4 o;
    if (row >= NPROJ) {
        o.x = o.y = o.z = o.w = 0;
    } else {
        const float* W;
        if      (row < 512)  W = Wsq + (size_t)row*DIM_;
        else if (row < 1024) W = Wsk + (size_t)(row-512)*DIM_;
        else if (row < 1536) W = Wsv + (size_t)(row-1024)*DIM_;
        else if (row < 1632) W = Wpq + (size_t)(row-1536)*DIM_;
        else if (row < 1728) W = Wpk + (size_t)(row-1632)*DIM_;
        else                 W = Wpv + (size_t)(row-1728)*DIM_;
        float4 v = reinterpret_cast<const float4*>(W)[c4];
        o.x = f2bf(v.x); o.y = f2bf(v.y); o.z = f2bf(v.z); o.w = f2bf(v.w);
    }
    reinterpret_cast<ushort4*>(wb)[i] = o;
}

// ---------------------------------------------------------------------------
// K1: projection GEMM via MFMA.  C[2048][1920] = xb[2048][768] . wb[1920][768]^T
// 128x128 tile, BK=32, 256 threads (4 waves as 2x2 of 64x64).
// Epilogue scatters into qs/ks/vs/praw layouts.
// ---------------------------------------------------------------------------
__global__ __launch_bounds__(256) void k_proj_mfma(
    const unsigned short* __restrict__ xb,
    const unsigned short* __restrict__ wb,
    float* __restrict__ ws)
{
    __shared__ unsigned short sAB[2*128*32];   // A tile then B tile, row-major [128][32]
    const int tid  = threadIdx.x;
    const int lane = tid & 63;
    const int wid  = tid >> 6;
    const int mt = blockIdx.x & 15;
    const int nt = blockIdx.x >> 4;
    const int row0 = mt*128;
    const int col0 = nt*128;
    const int wr = (wid >> 1)*64;
    const int wc = (wid & 1)*64;

    f32x4 acc[4][4];
    #pragma unroll
    for (int m = 0; m < 4; ++m)
        #pragma unroll
        for (int n = 0; n < 4; ++n) acc[m][n] = (f32x4){0.f,0.f,0.f,0.f};

    for (int kt = 0; kt < DIM_/32; ++kt) {
        __syncthreads();
        // stage 16 KB: 16 chunks of 1KB (16 rows x 64B); wave w does chunks w,w+4,w+8,w+12
        #pragma unroll
        for (int t = 0; t < 4; ++t) {
            int chunk = t*4 + wid;
            int tile  = chunk >> 3;                  // 0 = A(x), 1 = B(w)
            int crow  = (chunk & 7) * 16;
            int grow  = (tile ? col0 : row0) + crow + (lane >> 2);
            const unsigned short* gsrc = (tile ? wb : xb)
                + (size_t)grow*DIM_ + kt*32 + (lane & 3)*8;
            __builtin_amdgcn_global_load_lds(
                (const __attribute__((address_space(1))) void*)gsrc,
                (__attribute__((address_space(3))) void*)(sAB + chunk*512),
                16, 0, 0);
        }
        __syncthreads();

        bf16x8 a[4], b[4];
        #pragma unroll
        for (int m = 0; m < 4; ++m)
            a[m] = *reinterpret_cast<const bf16x8*>(
                sAB + ((wr + m*16 + (lane & 15))*32 + (lane >> 4)*8));
        #pragma unroll
        for (int n = 0; n < 4; ++n)
            b[n] = *reinterpret_cast<const bf16x8*>(
                sAB + 128*32 + ((wc + n*16 + (lane & 15))*32 + (lane >> 4)*8));
        #pragma unroll
        for (int m = 0; m < 4; ++m)
            #pragma unroll
            for (int n = 0; n < 4; ++n)
                acc[m][n] = __builtin_amdgcn_mfma_f32_16x16x32_bf16(
                    a[m], b[n], acc[m][n], 0, 0, 0);
    }

    float* ws_qs = ws + OFF_QS;
    float* ws_ks = ws + OFF_KS;
    float* ws_vs = ws + OFF_VS;
    float* ws_praw = ws + OFF_PRAW;

    #pragma unroll
    for (int n = 0; n < 4; ++n) {
        int o = col0 + wc + n*16 + (lane & 15);
        if (o >= NPROJ) continue;
        int is_s = (o < 1536);
        float* dstbase;
        size_t dstoff = 0;
        int h = 0, c = 0;
        if (is_s) {
            int wi = o >> 9;
            h = (o >> 6) & 7; c = o & 63;
            dstbase = (wi == 0) ? ws_qs : (wi == 1) ? ws_ks : ws_vs;
        } else {
            dstbase = ws_praw;
            dstoff = o - 1536;
        }
        #pragma unroll
        for (int m = 0; m < 4; ++m) {
            #pragma unroll
            for (int j = 0; j < 4; ++j) {
                int r = row0 + wr + m*16 + (lane >> 4)*4 + j;
                int bb = r >> 10, nn = r & (N_-1);
                float v = acc[m][n][j];
                if (is_s)
                    dstbase[(((size_t)(bb*H_ + h))*N_ + nn)*DH_ + c] = v;
                else
                    dstbase[(size_t)r*288 + dstoff] = v;
            }
        }
    }
}

// ---------------------------------------------------------------------------
// K2: rotate points + q2/k2. grid = B*N, block = 128.
// ---------------------------------------------------------------------------
__global__ __launch_bounds__(128) void k_rot(
    const float* __restrict__ rotations,
    const float* __restrict__ translations,
    float* __restrict__ ws)
{
    __shared__ float R[9], T[3];
    __shared__ float partial[2][8][4];
    const int tid = threadIdx.x;
    const int row = blockIdx.x;
    const int b = row >> 10, n = row & (N_-1);

    if (tid < 9)  R[tid] = rotations[(size_t)row*9 + tid];
    if (tid >= 9 && tid < 12) T[tid-9] = translations[(size_t)row*3 + (tid-9)];
    __syncthreads();

    if (tid < 96) {
        int which = tid / 32;      // 0=q,1=k,2=v
        int idx = tid & 31;
        int h = idx >> 2, pd = idx & 3;
        const float* p = ws + OFF_PRAW + (size_t)row*288 + which*96 + h*12 + pd*3;
        float px = p[0], py = p[1], pz = p[2];
        float c0 = R[0]*px + R[1]*py + R[2]*pz + T[0];
        float c1 = R[3]*px + R[4]*py + R[5]*pz + T[1];
        float c2 = R[6]*px + R[7]*py + R[8]*pz + T[2];
        float* dst = ws + (which == 0 ? OFF_QP : which == 1 ? OFF_KP : OFF_VP)
                   + (((size_t)(b*H_ + h))*N_ + n)*12 + pd*3;
        dst[0] = c0; dst[1] = c1; dst[2] = c2;
        if (which < 2) partial[which][h][pd] = c0*c0 + c1*c1 + c2*c2;
    }
    __syncthreads();
    if (tid < 16) {
        int which = tid >> 3, h = tid & 7;
        float s = partial[which][h][0] + partial[which][h][1]
                + partial[which][h][2] + partial[which][h][3];
        float* dst = ws + (which == 0 ? OFF_Q2 : OFF_K2);
        dst[(size_t)(b*H_ + h)*N_ + n] = s;
    }
}

// ---------------------------------------------------------------------------
// K3: attention. grid = B*H*(N/32) = 512, block = 256.
// ---------------------------------------------------------------------------
__global__ __launch_bounds__(256) void k_attn(
    const float* __restrict__ point_weights,
    float* __restrict__ ws)
{
    __shared__ float sKs[64*64];
    __shared__ float sVs[64*64];
    __shared__ float sKp[64*12];
    __shared__ float sVp[64*12];
    __shared__ float sK2[64];
    __shared__ float sP[32*65];
    __shared__ float sPmax[32*9];
    __shared__ float sPsum[32*9];

    const int tid = threadIdx.x;
    const int q  = tid & 31;
    const int g  = tid >> 5;
    const int qt = blockIdx.x & 31;
    const int bh = blockIdx.x >> 5;
    const int h  = bh & 7;
    const int q0 = qt * 32;

    const float scalar_scale = 0.08838834764831845f;   // (2*64)^-0.5
    const float point_scale  = 1.0f / 6.0f;            // (2*4*4.5)^-0.5
    const float pw = log1pf(expf(point_weights[h]));
    const float coef = 0.5f * pw * point_scale;

    const float* ws_qs = ws + OFF_QS + (size_t)bh*N_*DH_;
    const float* ws_ks = ws + OFF_KS + (size_t)bh*N_*DH_;
    const float* ws_vs = ws + OFF_VS + (size_t)bh*N_*DH_;
    const float* ws_qp = ws + OFF_QP + (size_t)bh*N_*12;
    const float* ws_kp = ws + OFF_KP + (size_t)bh*N_*12;
    const float* ws_vp = ws + OFF_VP + (size_t)bh*N_*12;
    const float* ws_q2 = ws + OFF_Q2 + (size_t)bh*N_;
    const float* ws_k2 = ws + OFF_K2 + (size_t)bh*N_;
    float* ws_rs = ws + OFF_RS + (size_t)bh*N_*DH_;
    float* ws_rp = ws + OFF_RP + (size_t)bh*N_*12;

    float4 qr[16];
    {
        const float4* src = reinterpret_cast<const float4*>(ws_qs + (size_t)(q0 + q)*DH_);
        #pragma unroll
        for (int c = 0; c < 16; ++c) qr[c] = src[c];
    }
    float qp_r[12];
    #pragma unroll
    for (int d = 0; d < 12; ++d) qp_r[d] = ws_qp[(size_t)(q0 + q)*12 + d];
    const float q2v = ws_q2[q0 + q];

    float m = -1e30f, l = 0.f;
    float accs[8];
    #pragma unroll
    for (int k = 0; k < 8; ++k) accs[k] = 0.f;
    float accp0 = 0.f, accp1 = 0.f;

    for (int jt = 0; jt < N_/64; ++jt) {
        const int j0 = jt * 64;
        __syncthreads();
        {
            const float4* src = reinterpret_cast<const float4*>(ws_ks + (size_t)j0*DH_);
            float4* dst = reinterpret_cast<float4*>(sKs);
            for (int i = tid; i < 1024; i += 256) dst[i] = src[i];
            src = reinterpret_cast<const float4*>(ws_vs + (size_t)j0*DH_);
            dst = reinterpret_cast<float4*>(sVs);
            for (int i = tid; i < 1024; i += 256) dst[i] = src[i];
            if (tid < 192) {
                reinterpret_cast<float4*>(sKp)[tid] =
                    reinterpret_cast<const float4*>(ws_kp + (size_t)j0*12)[tid];
                reinterpret_cast<float4*>(sVp)[tid] =
                    reinterpret_cast<const float4*>(ws_vp + (size_t)j0*12)[tid];
            }
            if (tid < 64) sK2[tid] = ws_k2[j0 + tid];
        }
        __syncthreads();

        float s[8];
        float lmax = -1e30f;
        #pragma unroll
        for (int jj = 0; jj < 8; ++jj) {
            int j = g*8 + jj;
            const float4* kr = reinterpret_cast<const float4*>(&sKs[j*64]);
            float dot = 0.f;
            #pragma unroll
            for (int c = 0; c < 16; ++c) dot += dot4(qr[c], kr[c]);
            float qk = 0.f;
            #pragma unroll
            for (int d = 0; d < 12; ++d) qk += qp_r[d] * sKp[j*12 + d];
            float sv = dot*scalar_scale + 2.f*coef*qk - coef*(q2v + sK2[j]);
            s[jj] = sv;
            lmax = fmaxf(lmax, sv);
        }
        sPmax[q*9 + g] = lmax;
        __syncthreads();

        float mnew = m;
        #pragma unroll
        for (int gg = 0; gg < 8; ++gg) mnew = fmaxf(mnew, sPmax[q*9 + gg]);
        const float scale = __expf(m - mnew);
        float psum = 0.f;
        #pragma unroll
        for (int jj = 0; jj < 8; ++jj) {
            float p = __expf(s[jj] - mnew);
            sP[q*65 + g*8 + jj] = p;
            psum += p;
        }
        sPsum[q*9 + g] = psum;
        __syncthreads();

        float tots = 0.f;
        #pragma unroll
        for (int gg = 0; gg < 8; ++gg) tots += sPsum[q*9 + gg];
        l = l*scale + tots;
        m = mnew;
        #pragma unroll
        for (int k = 0; k < 8; ++k) accs[k] *= scale;
        accp0 *= scale; accp1 *= scale;

        for (int j = 0; j < 64; ++j) {
            float p = sP[q*65 + j];
            const float4* vr = reinterpret_cast<const float4*>(&sVs[j*64 + g*8]);
            float4 v0 = vr[0], v1 = vr[1];
            accs[0] += p*v0.x; accs[1] += p*v0.y; accs[2] += p*v0.z; accs[3] += p*v0.w;
            accs[4] += p*v1.x; accs[5] += p*v1.y; accs[6] += p*v1.z; accs[7] += p*v1.w;
            if (g < 6) {
                accp0 += p * sVp[j*12 + 2*g];
                accp1 += p * sVp[j*12 + 2*g + 1];
            }
        }
    }

    const float inv = 1.0f / l;
    float* dsts = ws_rs + (size_t)(q0 + q)*DH_ + g*8;
    #pragma unroll
    for (int k = 0; k < 8; ++k) dsts[k] = accs[k] * inv;
    if (g < 6) {
        float* dstp = ws_rp + (size_t)(q0 + q)*12 + 2*g;
        dstp[0] = accp0 * inv;
        dstp[1] = accp1 * inv;
    }
}

// ---------------------------------------------------------------------------
// K4: finalize + output GEMM. grid = B*N/8 = 256, block = 256.
// ---------------------------------------------------------------------------
__global__ __launch_bounds__(256) void k_fin(
    const float* __restrict__ rotations,
    const float* __restrict__ translations,
    const float* __restrict__ Wout,
    const float* __restrict__ bout,
    const float* __restrict__ ws,
    float* __restrict__ out)
{
    __shared__ float sF[8][640];
    const int tid = threadIdx.x;
    const int row0 = blockIdx.x * 8;
    const int b = row0 >> 10;
    const float* ws_rs = ws + OFF_RS;
    const float* ws_rp = ws + OFF_RP;

    for (int i = tid; i < 8*512; i += 256) {
        int r = i >> 9, f = i & 511;
        int h = f >> 6, c = f & 63;
        int n = (row0 & (N_-1)) + r;
        sF[r][f] = ws_rs[(((size_t)(b*H_ + h))*N_ + n)*DH_ + c];
    }
    {
        int r = tid >> 5;
        int idx = tid & 31;
        int h = idx >> 2, pd = idx & 3;
        int row = row0 + r;
        int n = row & (N_-1);
        const float* rp = ws_rp + (((size_t)(b*H_ + h))*N_ + n)*12 + pd*3;
        const float* R = rotations + (size_t)row*9;
        const float* T = translations + (size_t)row*3;
        float d0 = rp[0] - T[0], d1 = rp[1] - T[1], d2 = rp[2] - T[2];
        float l0 = R[0]*d0 + R[3]*d1 + R[6]*d2;
        float l1 = R[1]*d0 + R[4]*d1 + R[7]*d2;
        float l2 = R[2]*d0 + R[5]*d1 + R[8]*d2;
        sF[r][512 + h*12 + pd*3 + 0] = l0;
        sF[r][512 + h*12 + pd*3 + 1] = l1;
        sF[r][512 + h*12 + pd*3 + 2] = l2;
        sF[r][608 + h*4 + pd] = sqrtf(l0*l0 + l1*l1 + l2*l2 + 1e-8f);
    }
    __syncthreads();

    for (int o = tid; o < DIM_; o += 256) {
        float acc[8];
        #pragma unroll
        for (int r = 0; r < 8; ++r) acc[r] = 0.f;
        const float4* wr = reinterpret_cast<const float4*>(Wout + (size_t)o*640);
        for (int f4 = 0; f4 < 160; ++f4) {
            float4 w = wr[f4];
            #pragma unroll
            for (int r = 0; r < 8; ++r) {
                const float4 fv = reinterpret_cast<const float4*>(sF[r])[f4];
                acc[r] += dot4(w, fv);
            }
        }
        float bo = bout[o];
        #pragma unroll
        for (int r = 0; r < 8; ++r) {
            out[(size_t)(row0 + r)*DIM_ + o] = acc[r] + bo;
        }
    }
}

// ---------------------------------------------------------------------------
extern "C" void kernel_launch(void* const* d_in, const int* in_sizes, int n_in,
                              void* d_out, int out_size, void* d_ws, size_t ws_size,
                              hipStream_t stream) {
    const float* x            = (const float*)d_in[0];
    const float* rotations    = (const float*)d_in[1];
    const float* translations = (const float*)d_in[2];
    const float* Wsq          = (const float*)d_in[3];
    const float* Wsk          = (const float*)d_in[4];
    const float* Wsv          = (const float*)d_in[5];
    const float* Wpq          = (const float*)d_in[6];
    const float* Wpk          = (const float*)d_in[7];
    const float* Wpv          = (const float*)d_in[8];
    const float* pweights     = (const float*)d_in[9];
    const float* Wout         = (const float*)d_in[10];
    const float* bout         = (const float*)d_in[11];
    float* out = (float*)d_out;
    float* ws  = (float*)d_ws;

    unsigned short* xb = (unsigned short*)(ws + OFF_XB);
    unsigned short* wb = (unsigned short*)(ws + OFF_WB);

    k_cvt_x<<<(B_*N_*DIM_/4 + 255)/256, 256, 0, stream>>>(x, xb);
    k_cvt_w<<<(NPAD*DIM_/4 + 255)/256, 256, 0, stream>>>(Wsq, Wsk, Wsv, Wpq, Wpk, Wpv, wb);
    k_proj_mfma<<<16*15, 256, 0, stream>>>(xb, wb, ws);
    k_rot<<<B_*N_, 128, 0, stream>>>(rotations, translations, ws);
    k_attn<<<BH_*(N_/32), 256, 0, stream>>>(pweights, ws);
    k_fin<<<B_*N_/8, 256, 0, stream>>>(rotations, translations, Wout, bout, ws, out);
}

// Round 3
// 213.711 us; speedup vs baseline: 3.3539x; 1.7208x over previous
//
#include <hip/hip_runtime.h>
#include <hip/hip_bf16.h>
#include <math.h>

// Problem constants
#define B_  2
#define N_  1024
#define DIM_ 768
#define H_  8
#define DH_ 64
#define PD_ 4
#define NPROJ 1824            // 3*512 + 3*96
#define NPAD  1920            // padded to 15*128
#define BH_ (B_*H_)           // 16

// ws layout (float offsets)
#define OFF_RS   0u
#define OFF_RP   (OFF_RS + (size_t)BH_*N_*DH_)          // 1048576
#define OFF_PRAW (OFF_RP + (size_t)BH_*N_*12)           // +196608
#define OFF_QA   (OFF_PRAW + (size_t)B_*N_*288)         // +589824 ; bf16 [16][1024][96]
#define OFF_KA   (OFF_QA + (size_t)BH_*N_*96/2)         // +786432
#define OFF_VT   (OFF_KA + (size_t)BH_*N_*96/2)         // bf16 [16][80][1024]
#define OFF_XB   (OFF_VT + (size_t)BH_*80*N_/2)         // bf16 x
#define OFF_WB   (OFF_XB + (size_t)B_*N_*DIM_/2)        // bf16 packed W

typedef __attribute__((ext_vector_type(8))) short bf16x8;
typedef __attribute__((ext_vector_type(4))) float f32x4;
typedef unsigned short ushort_t;

__device__ __forceinline__ float dot4(float4 a, float4 b) {
    return a.x*b.x + a.y*b.y + a.z*b.z + a.w*b.w;
}
__device__ __forceinline__ unsigned short f2bf(float f) {
    __hip_bfloat16 h = __float2bfloat16(f);
    return *reinterpret_cast<unsigned short*>(&h);
}

// ---------------------------------------------------------------------------
// convert x -> bf16
// ---------------------------------------------------------------------------
__global__ __launch_bounds__(256) void k_cvt_x(
    const float* __restrict__ x, unsigned short* __restrict__ xb)
{
    int i = blockIdx.x * 256 + threadIdx.x;
    if (i >= (B_*N_*DIM_)/4) return;
    float4 v = reinterpret_cast<const float4*>(x)[i];
    ushort4 o;
    o.x = f2bf(v.x); o.y = f2bf(v.y); o.z = f2bf(v.z); o.w = f2bf(v.w);
    reinterpret_cast<ushort4*>(xb)[i] = o;
}

// ---------------------------------------------------------------------------
// pack 6 weight mats into wb[1920][768] bf16
// ---------------------------------------------------------------------------
__global__ __launch_bounds__(256) void k_cvt_w(
    const float* __restrict__ Wsq, const float* __restrict__ Wsk,
    const float* __restrict__ Wsv, const float* __restrict__ Wpq,
    const float* __restrict__ Wpk, const float* __restrict__ Wpv,
    unsigned short* __restrict__ wb)
{
    int i = blockIdx.x * 256 + threadIdx.x;
    if (i >= (NPAD*DIM_)/4) return;
    int row = i / (DIM_/4);
    int c4  = i % (DIM_/4);
    ushort4 o;
    if (row >= NPROJ) {
        o.x = o.y = o.z = o.w = 0;
    } else {
        const float* W;
        if      (row < 512)  W = Wsq + (size_t)row*DIM_;
        else if (row < 1024) W = Wsk + (size_t)(row-512)*DIM_;
        else if (row < 1536) W = Wsv + (size_t)(row-1024)*DIM_;
        else if (row < 1632) W = Wpq + (size_t)(row-1536)*DIM_;
        else if (row < 1728) W = Wpk + (size_t)(row-1632)*DIM_;
        else                 W = Wpv + (size_t)(row-1728)*DIM_;
        float4 v = reinterpret_cast<const float4*>(W)[c4];
        o.x = f2bf(v.x); o.y = f2bf(v.y); o.z = f2bf(v.z); o.w = f2bf(v.w);
    }
    reinterpret_cast<ushort4*>(wb)[i] = o;
}

// ---------------------------------------------------------------------------
// K1: projection GEMM via MFMA; epilogue writes Qa/Ka/Vt (bf16) + praw (f32)
// ---------------------------------------------------------------------------
__global__ __launch_bounds__(256) void k_proj_mfma(
    const unsigned short* __restrict__ xb,
    const unsigned short* __restrict__ wb,
    float* __restrict__ ws)
{
    __shared__ unsigned short sAB[2*128*32];
    const int tid  = threadIdx.x;
    const int lane = tid & 63;
    const int wid  = tid >> 6;
    const int mt = blockIdx.x & 15;
    const int nt = blockIdx.x >> 4;
    const int row0 = mt*128;
    const int col0 = nt*128;
    const int wr = (wid >> 1)*64;
    const int wc = (wid & 1)*64;

    f32x4 acc[4][4];
    #pragma unroll
    for (int m = 0; m < 4; ++m)
        #pragma unroll
        for (int n = 0; n < 4; ++n) acc[m][n] = (f32x4){0.f,0.f,0.f,0.f};

    for (int kt = 0; kt < DIM_/32; ++kt) {
        __syncthreads();
        #pragma unroll
        for (int t = 0; t < 4; ++t) {
            int chunk = t*4 + wid;
            int tile  = chunk >> 3;
            int crow  = (chunk & 7) * 16;
            int grow  = (tile ? col0 : row0) + crow + (lane >> 2);
            const unsigned short* gsrc = (tile ? wb : xb)
                + (size_t)grow*DIM_ + kt*32 + (lane & 3)*8;
            __builtin_amdgcn_global_load_lds(
                (const __attribute__((address_space(1))) void*)gsrc,
                (__attribute__((address_space(3))) void*)(sAB + chunk*512),
                16, 0, 0);
        }
        __syncthreads();

        bf16x8 a[4], b[4];
        #pragma unroll
        for (int m = 0; m < 4; ++m)
            a[m] = *reinterpret_cast<const bf16x8*>(
                sAB + ((wr + m*16 + (lane & 15))*32 + (lane >> 4)*8));
        #pragma unroll
        for (int n = 0; n < 4; ++n)
            b[n] = *reinterpret_cast<const bf16x8*>(
                sAB + 128*32 + ((wc + n*16 + (lane & 15))*32 + (lane >> 4)*8));
        #pragma unroll
        for (int m = 0; m < 4; ++m)
            #pragma unroll
            for (int n = 0; n < 4; ++n)
                acc[m][n] = __builtin_amdgcn_mfma_f32_16x16x32_bf16(
                    a[m], b[n], acc[m][n], 0, 0, 0);
    }

    unsigned short* qa = (unsigned short*)(ws + OFF_QA);
    unsigned short* ka = (unsigned short*)(ws + OFF_KA);
    unsigned short* vt = (unsigned short*)(ws + OFF_VT);
    float* praw = ws + OFF_PRAW;
    const float ss = 0.08838834764831845f;   // (2*64)^-0.5

    #pragma unroll
    for (int n = 0; n < 4; ++n) {
        int o = col0 + wc + n*16 + (lane & 15);
        if (o >= NPROJ) continue;
        #pragma unroll
        for (int m = 0; m < 4; ++m) {
            #pragma unroll
            for (int j = 0; j < 4; ++j) {
                int r = row0 + wr + m*16 + (lane >> 4)*4 + j;
                int bb = r >> 10, nn = r & (N_-1);
                float v = acc[m][n][j];
                if (o < 512) {
                    int h = o >> 6, c = o & 63;
                    qa[((size_t)(bb*H_ + h)*N_ + nn)*96 + c] = f2bf(v*ss);
                } else if (o < 1024) {
                    int oo = o - 512; int h = oo >> 6, c = oo & 63;
                    ka[((size_t)(bb*H_ + h)*N_ + nn)*96 + c] = f2bf(v);
                } else if (o < 1536) {
                    int oo = o - 1024; int h = oo >> 6, c = oo & 63;
                    vt[((size_t)(bb*H_ + h)*80 + c)*N_ + nn] = f2bf(v);
                } else {
                    praw[(size_t)r*288 + (o - 1536)] = v;
                }
            }
        }
    }
}

// ---------------------------------------------------------------------------
// K2: rotate points, q2/k2, write Qa/Ka tails + Vt point rows (+ zero pads)
// grid = B*N blocks x 128 threads
// ---------------------------------------------------------------------------
__global__ __launch_bounds__(128) void k_prep(
    const float* __restrict__ rot_g,
    const float* __restrict__ trans_g,
    const float* __restrict__ pw_g,
    float* __restrict__ ws)
{
    __shared__ float R[9], T[3];
    __shared__ float rot[3][8][4][3];
    __shared__ float p2[2][8][4];
    __shared__ float q2t[8], k2t[8], coefs[8];
    const int tid = threadIdx.x;
    const int row = blockIdx.x;
    const int b = row >> 10, n = row & (N_-1);

    if (tid < 9)  R[tid] = rot_g[(size_t)row*9 + tid];
    if (tid >= 9 && tid < 12) T[tid-9] = trans_g[(size_t)row*3 + (tid-9)];
    if (tid >= 16 && tid < 24) {
        float pw = pw_g[tid-16];
        coefs[tid-16] = 0.5f * log1pf(__expf(pw)) * (1.0f/6.0f);
    }
    __syncthreads();
    if (tid < 96) {
        int which = tid >> 5, idx = tid & 31;
        int h = idx >> 2, pd = idx & 3;
        const float* p = ws + OFF_PRAW + (size_t)row*288 + which*96 + h*12 + pd*3;
        float px = p[0], py = p[1], pz = p[2];
        float c0 = R[0]*px + R[1]*py + R[2]*pz + T[0];
        float c1 = R[3]*px + R[4]*py + R[5]*pz + T[1];
        float c2 = R[6]*px + R[7]*py + R[8]*pz + T[2];
        rot[which][h][pd][0] = c0;
        rot[which][h][pd][1] = c1;
        rot[which][h][pd][2] = c2;
        if (which < 2) p2[which][h][pd] = c0*c0 + c1*c1 + c2*c2;
    }
    __syncthreads();
    if (tid < 16) {
        int w = tid >> 3, h = tid & 7;
        float s = p2[w][h][0] + p2[w][h][1] + p2[w][h][2] + p2[w][h][3];
        if (w) k2t[h] = s; else q2t[h] = s;
    }
    __syncthreads();

    unsigned short* qa = (unsigned short*)(ws + OFF_QA);
    unsigned short* ka = (unsigned short*)(ws + OFF_KA);
    unsigned short* vt = (unsigned short*)(ws + OFF_VT);

    for (int i = tid; i < 256; i += 128) {
        int h = i >> 5, c = i & 31;
        float qv, kv;
        if (c < 12)      { qv = rot[0][h][c/3][c%3] * 2.f * coefs[h]; kv = rot[1][h][c/3][c%3]; }
        else if (c == 12){ qv = q2t[h];  kv = -coefs[h]; }
        else if (c == 13){ qv = 1.f;     kv = -coefs[h]*k2t[h]; }
        else             { qv = 0.f;     kv = 0.f; }
        size_t base = ((size_t)(b*H_ + h)*N_ + n)*96 + 64 + c;
        qa[base] = f2bf(qv);
        ka[base] = f2bf(kv);
    }
    {
        int h = tid >> 4, r = tid & 15;
        float vv = (r < 12) ? rot[2][h][r/3][r%3] : 0.f;
        vt[((size_t)(b*H_ + h)*80 + 64 + r)*N_ + n] = f2bf(vv);
    }
}

// ---------------------------------------------------------------------------
// K3: MFMA flash attention.
// grid = 16 bh x 32 qtiles = 512 blocks, 256 threads (4 waves).
// wave w: rows (w&1)*16 of the 32-row Q tile; k-half = w>>1 (8 tiles of 64).
// ---------------------------------------------------------------------------
#define KPAD 104
#define VPAD 72
__global__ __launch_bounds__(256) void k_attn_mfma(
    const unsigned short* __restrict__ qa_g,
    const unsigned short* __restrict__ ka_g,
    const unsigned short* __restrict__ vt_g,
    float* __restrict__ ws)
{
    __shared__ unsigned short sKa[2][64*KPAD];
    __shared__ unsigned short sVt[2][80*VPAD];
    __shared__ unsigned short sP[4][16*VPAD];
    __shared__ float sMrg[32*80];
    __shared__ float sML[32*2];

    const int tid  = threadIdx.x;
    const int lane = tid & 63;
    const int wid  = tid >> 6;
    const int bh = blockIdx.x >> 5;
    const int qt = blockIdx.x & 31;
    const int q0 = qt * 32;
    const int mrow = (wid & 1) * 16;
    const int half = wid >> 1;
    const int tg   = tid & 127;        // index within staging group (== half)

    const unsigned short* Qa = qa_g + (size_t)bh*N_*96;
    const unsigned short* Ka = ka_g + (size_t)bh*N_*96;
    const unsigned short* Vt = vt_g + (size_t)bh*80*N_;

    // Q fragments (M=16 rows per wave), 3 K-chunks
    bf16x8 qfr[3];
    {
        int qrow = q0 + mrow + (lane & 15);
        #pragma unroll
        for (int c = 0; c < 3; ++c)
            qfr[c] = *reinterpret_cast<const bf16x8*>(
                Qa + (size_t)qrow*96 + c*32 + (lane >> 4)*8);
    }

    f32x4 acc[5];
    #pragma unroll
    for (int d = 0; d < 5; ++d) acc[d] = (f32x4){0.f,0.f,0.f,0.f};
    float m[4] = {-1e30f,-1e30f,-1e30f,-1e30f};
    float l[4] = {0.f,0.f,0.f,0.f};

    for (int it = 0; it < 8; ++it) {
        const int j0 = (half*8 + it)*64;
        __syncthreads();
        // stage Ka tile [64][96] -> sKa[half] (stride 104)
        for (int i = tg; i < 768; i += 128) {
            int r = i / 12, c = i % 12;
            *reinterpret_cast<uint4*>(&sKa[half][r*KPAD + c*8]) =
                *reinterpret_cast<const uint4*>(Ka + (size_t)(j0+r)*96 + c*8);
        }
        // stage Vt tile [80][64] -> sVt[half] (stride 72)
        for (int i = tg; i < 640; i += 128) {
            int r = i >> 3, c = i & 7;
            *reinterpret_cast<uint4*>(&sVt[half][r*VPAD + c*8]) =
                *reinterpret_cast<const uint4*>(Vt + (size_t)r*N_ + j0 + c*8);
        }
        __syncthreads();

        // S = Qa . Ka^T  (M=16, N=64 as 4 subtiles, K=96 as 3 chunks)
        f32x4 s[4];
        #pragma unroll
        for (int t = 0; t < 4; ++t) s[t] = (f32x4){0.f,0.f,0.f,0.f};
        #pragma unroll
        for (int c = 0; c < 3; ++c) {
            #pragma unroll
            for (int t = 0; t < 4; ++t) {
                bf16x8 kb = *reinterpret_cast<const bf16x8*>(
                    &sKa[half][(t*16 + (lane & 15))*KPAD + c*32 + (lane >> 4)*8]);
                s[t] = __builtin_amdgcn_mfma_f32_16x16x32_bf16(qfr[c], kb, s[t], 0, 0, 0);
            }
        }

        // online softmax; rows r: i = (lane>>4)*4 + r, cols j = t*16 + (lane&15)
        float scl[4];
        #pragma unroll
        for (int r = 0; r < 4; ++r) {
            float v = fmaxf(fmaxf(s[0][r], s[1][r]), fmaxf(s[2][r], s[3][r]));
            v = fmaxf(v, __shfl_xor(v, 1));
            v = fmaxf(v, __shfl_xor(v, 2));
            v = fmaxf(v, __shfl_xor(v, 4));
            v = fmaxf(v, __shfl_xor(v, 8));
            float mn = fmaxf(m[r], v);
            scl[r] = __expf(m[r] - mn);
            m[r] = mn;
        }
        float ps[4] = {0.f,0.f,0.f,0.f};
        #pragma unroll
        for (int t = 0; t < 4; ++t) {
            #pragma unroll
            for (int r = 0; r < 4; ++r) {
                float p = __expf(s[t][r] - m[r]);
                ps[r] += p;
                sP[wid][((lane >> 4)*4 + r)*VPAD + t*16 + (lane & 15)] = f2bf(p);
            }
        }
        #pragma unroll
        for (int r = 0; r < 4; ++r) {
            float v = ps[r];
            v += __shfl_xor(v, 1);
            v += __shfl_xor(v, 2);
            v += __shfl_xor(v, 4);
            v += __shfl_xor(v, 8);
            l[r] = l[r]*scl[r] + v;
        }
        #pragma unroll
        for (int d = 0; d < 5; ++d)
            #pragma unroll
            for (int r = 0; r < 4; ++r) acc[d][r] *= scl[r];

        // PV: O += P . V   (K=64 as 2 chunks, N=80 as 5 subtiles)
        #pragma unroll
        for (int kk = 0; kk < 2; ++kk) {
            bf16x8 pa = *reinterpret_cast<const bf16x8*>(
                &sP[wid][(lane & 15)*VPAD + kk*32 + (lane >> 4)*8]);
            #pragma unroll
            for (int dt = 0; dt < 5; ++dt) {
                bf16x8 vb = *reinterpret_cast<const bf16x8*>(
                    &sVt[half][(dt*16 + (lane & 15))*VPAD + kk*32 + (lane >> 4)*8]);
                acc[dt] = __builtin_amdgcn_mfma_f32_16x16x32_bf16(pa, vb, acc[dt], 0, 0, 0);
            }
        }
    }

    // merge the two k-halves
    __syncthreads();
    if (half == 1) {
        #pragma unroll
        for (int r = 0; r < 4; ++r) {
            int rl = mrow + (lane >> 4)*4 + r;
            #pragma unroll
            for (int dt = 0; dt < 5; ++dt)
                sMrg[rl*80 + dt*16 + (lane & 15)] = acc[dt][r];
            if ((lane & 15) == 0) { sML[rl*2] = m[r]; sML[rl*2+1] = l[r]; }
        }
    }
    __syncthreads();
    if (half == 0) {
        float* ws_rs = ws + OFF_RS + (size_t)bh*N_*DH_;
        float* ws_rp = ws + OFF_RP + (size_t)bh*N_*12;
        #pragma unroll
        for (int r = 0; r < 4; ++r) {
            int rl = mrow + (lane >> 4)*4 + r;
            float m2 = sML[rl*2], l2 = sML[rl*2+1];
            float mm = fmaxf(m[r], m2);
            float f1 = __expf(m[r] - mm), f2 = __expf(m2 - mm);
            float inv = 1.f / (l[r]*f1 + l2*f2);
            int i = q0 + rl;
            #pragma unroll
            for (int dt = 0; dt < 5; ++dt) {
                float val = (acc[dt][r]*f1 + sMrg[rl*80 + dt*16 + (lane & 15)]*f2) * inv;
                int d = dt*16 + (lane & 15);
                if (d < 64)
                    ws_rs[(size_t)i*DH_ + d] = val;
                else if (d - 64 < 12)
                    ws_rp[(size_t)i*12 + (d - 64)] = val;
            }
        }
    }
}

// ---------------------------------------------------------------------------
// K4: finalize + output GEMM. grid = B*N/8 = 256, block = 256.
// ---------------------------------------------------------------------------
__global__ __launch_bounds__(256) void k_fin(
    const float* __restrict__ rotations,
    const float* __restrict__ translations,
    const float* __restrict__ Wout,
    const float* __restrict__ bout,
    const float* __restrict__ ws,
    float* __restrict__ out)
{
    __shared__ float sF[8][640];
    const int tid = threadIdx.x;
    const int row0 = blockIdx.x * 8;
    const int b = row0 >> 10;
    const float* ws_rs = ws + OFF_RS;
    const float* ws_rp = ws + OFF_RP;

    for (int i = tid; i < 8*512; i += 256) {
        int r = i >> 9, f = i & 511;
        int h = f >> 6, c = f & 63;
        int n = (row0 & (N_-1)) + r;
        sF[r][f] = ws_rs[(((size_t)(b*H_ + h))*N_ + n)*DH_ + c];
    }
    {
        int r = tid >> 5;
        int idx = tid & 31;
        int h = idx >> 2, pd = idx & 3;
        int row = row0 + r;
        int n = row & (N_-1);
        const float* rp = ws_rp + (((size_t)(b*H_ + h))*N_ + n)*12 + pd*3;
        const float* R = rotations + (size_t)row*9;
        const float* T = translations + (size_t)row*3;
        float d0 = rp[0] - T[0], d1 = rp[1] - T[1], d2 = rp[2] - T[2];
        float l0 = R[0]*d0 + R[3]*d1 + R[6]*d2;
        float l1 = R[1]*d0 + R[4]*d1 + R[7]*d2;
        float l2 = R[2]*d0 + R[5]*d1 + R[8]*d2;
        sF[r][512 + h*12 + pd*3 + 0] = l0;
        sF[r][512 + h*12 + pd*3 + 1] = l1;
        sF[r][512 + h*12 + pd*3 + 2] = l2;
        sF[r][608 + h*4 + pd] = sqrtf(l0*l0 + l1*l1 + l2*l2 + 1e-8f);
    }
    __syncthreads();

    for (int o = tid; o < DIM_; o += 256) {
        float acc[8];
        #pragma unroll
        for (int r = 0; r < 8; ++r) acc[r] = 0.f;
        const float4* wr = reinterpret_cast<const float4*>(Wout + (size_t)o*640);
        for (int f4 = 0; f4 < 160; ++f4) {
            float4 w = wr[f4];
            #pragma unroll
            for (int r = 0; r < 8; ++r) {
                const float4 fv = reinterpret_cast<const float4*>(sF[r])[f4];
                acc[r] += dot4(w, fv);
            }
        }
        float bo = bout[o];
        #pragma unroll
        for (int r = 0; r < 8; ++r) {
            out[(size_t)(row0 + r)*DIM_ + o] = acc[r] + bo;
        }
    }
}

// ---------------------------------------------------------------------------
extern "C" void kernel_launch(void* const* d_in, const int* in_sizes, int n_in,
                              void* d_out, int out_size, void* d_ws, size_t ws_size,
                              hipStream_t stream) {
    const float* x            = (const float*)d_in[0];
    const float* rotations    = (const float*)d_in[1];
    const float* translations = (const float*)d_in[2];
    const float* Wsq          = (const float*)d_in[3];
    const float* Wsk          = (const float*)d_in[4];
    const float* Wsv          = (const float*)d_in[5];
    const float* Wpq          = (const float*)d_in[6];
    const float* Wpk          = (const float*)d_in[7];
    const float* Wpv          = (const float*)d_in[8];
    const float* pweights     = (const float*)d_in[9];
    const float* Wout         = (const float*)d_in[10];
    const float* bout         = (const float*)d_in[11];
    float* out = (float*)d_out;
    float* ws  = (float*)d_ws;

    unsigned short* xb = (unsigned short*)(ws + OFF_XB);
    unsigned short* wb = (unsigned short*)(ws + OFF_WB);
    unsigned short* qa = (unsigned short*)(ws + OFF_QA);
    unsigned short* ka = (unsigned short*)(ws + OFF_KA);
    unsigned short* vt = (unsigned short*)(ws + OFF_VT);

    k_cvt_x<<<(B_*N_*DIM_/4 + 255)/256, 256, 0, stream>>>(x, xb);
    k_cvt_w<<<(NPAD*DIM_/4 + 255)/256, 256, 0, stream>>>(Wsq, Wsk, Wsv, Wpq, Wpk, Wpv, wb);
    k_proj_mfma<<<16*15, 256, 0, stream>>>(xb, wb, ws);
    k_prep<<<B_*N_, 128, 0, stream>>>(rotations, translations, pweights, ws);
    k_attn_mfma<<<BH_*32, 256, 0, stream>>>(qa, ka, vt, ws);
    k_fin<<<B_*N_/8, 256, 0, stream>>>(rotations, translations, Wout, bout, ws, out);
}

// Round 4
// 108.793 us; speedup vs baseline: 6.5885x; 1.9644x over previous
//
#include <hip/hip_runtime.h>
#include <hip/hip_bf16.h>
#include <math.h>

// Problem constants
#define B_  2
#define N_  1024
#define DIM_ 768
#define H_  8
#define DH_ 64
#define PD_ 4
#define NPROJ 1824            // 3*512 + 3*96
#define NPAD  1920            // padded to 15*128
#define BH_ (B_*H_)           // 16
#define FDIM 640              // output feature dim

// ws layout (float offsets)
#define OFF_RS   0u
#define OFF_RP   (OFF_RS + (size_t)BH_*N_*DH_)          // 1048576
#define OFF_PRAW (OFF_RP + (size_t)BH_*N_*12)           // +196608
#define OFF_QA   (OFF_PRAW + (size_t)B_*N_*288)         // +589824 ; bf16 [16][1024][96]
#define OFF_KA   (OFF_QA + (size_t)BH_*N_*96/2)         // +786432
#define OFF_VT   (OFF_KA + (size_t)BH_*N_*96/2)         // bf16 [16][80][1024]
#define OFF_XB   (OFF_VT + (size_t)BH_*80*N_/2)         // bf16 x  (later: fb)
#define OFF_WB   (OFF_XB + (size_t)B_*N_*DIM_/2)        // bf16 packed W (later: wob)
// reuse after projection:
#define OFF_FB   OFF_XB       // bf16 [2048][640]  (655360 float slots needed <= 786432)
#define OFF_WOB  OFF_WB       // bf16 [768][640]   (245760 <= 737280)

typedef __attribute__((ext_vector_type(8))) short bf16x8;
typedef __attribute__((ext_vector_type(4))) float f32x4;

__device__ __forceinline__ float dot4(float4 a, float4 b) {
    return a.x*b.x + a.y*b.y + a.z*b.z + a.w*b.w;
}
__device__ __forceinline__ unsigned short f2bf(float f) {
    __hip_bfloat16 h = __float2bfloat16(f);
    return *reinterpret_cast<unsigned short*>(&h);
}

// ---------------------------------------------------------------------------
// convert x -> bf16
// ---------------------------------------------------------------------------
__global__ __launch_bounds__(256) void k_cvt_x(
    const float* __restrict__ x, unsigned short* __restrict__ xb)
{
    int i = blockIdx.x * 256 + threadIdx.x;
    if (i >= (B_*N_*DIM_)/4) return;
    float4 v = reinterpret_cast<const float4*>(x)[i];
    ushort4 o;
    o.x = f2bf(v.x); o.y = f2bf(v.y); o.z = f2bf(v.z); o.w = f2bf(v.w);
    reinterpret_cast<ushort4*>(xb)[i] = o;
}

// ---------------------------------------------------------------------------
// pack 6 weight mats into wb[1920][768] bf16
// ---------------------------------------------------------------------------
__global__ __launch_bounds__(256) void k_cvt_w(
    const float* __restrict__ Wsq, const float* __restrict__ Wsk,
    const float* __restrict__ Wsv, const float* __restrict__ Wpq,
    const float* __restrict__ Wpk, const float* __restrict__ Wpv,
    unsigned short* __restrict__ wb)
{
    int i = blockIdx.x * 256 + threadIdx.x;
    if (i >= (NPAD*DIM_)/4) return;
    int row = i / (DIM_/4);
    int c4  = i % (DIM_/4);
    ushort4 o;
    if (row >= NPROJ) {
        o.x = o.y = o.z = o.w = 0;
    } else {
        const float* W;
        if      (row < 512)  W = Wsq + (size_t)row*DIM_;
        else if (row < 1024) W = Wsk + (size_t)(row-512)*DIM_;
        else if (row < 1536) W = Wsv + (size_t)(row-1024)*DIM_;
        else if (row < 1632) W = Wpq + (size_t)(row-1536)*DIM_;
        else if (row < 1728) W = Wpk + (size_t)(row-1632)*DIM_;
        else                 W = Wpv + (size_t)(row-1728)*DIM_;
        float4 v = reinterpret_cast<const float4*>(W)[c4];
        o.x = f2bf(v.x); o.y = f2bf(v.y); o.z = f2bf(v.z); o.w = f2bf(v.w);
    }
    reinterpret_cast<ushort4*>(wb)[i] = o;
}

// ---------------------------------------------------------------------------
// convert Wout[768][640] -> bf16
// ---------------------------------------------------------------------------
__global__ __launch_bounds__(256) void k_cvt_wout(
    const float* __restrict__ Wout, unsigned short* __restrict__ wob)
{
    int i = blockIdx.x * 256 + threadIdx.x;
    if (i >= (DIM_*FDIM)/4) return;
    float4 v = reinterpret_cast<const float4*>(Wout)[i];
    ushort4 o;
    o.x = f2bf(v.x); o.y = f2bf(v.y); o.z = f2bf(v.z); o.w = f2bf(v.w);
    reinterpret_cast<ushort4*>(wob)[i] = o;
}

// ---------------------------------------------------------------------------
// K1: projection GEMM via MFMA; epilogue writes Qa/Ka/Vt (bf16) + praw (f32)
// ---------------------------------------------------------------------------
__global__ __launch_bounds__(256) void k_proj_mfma(
    const unsigned short* __restrict__ xb,
    const unsigned short* __restrict__ wb,
    float* __restrict__ ws)
{
    __shared__ unsigned short sAB[2*128*32];
    const int tid  = threadIdx.x;
    const int lane = tid & 63;
    const int wid  = tid >> 6;
    const int mt = blockIdx.x & 15;
    const int nt = blockIdx.x >> 4;
    const int row0 = mt*128;
    const int col0 = nt*128;
    const int wr = (wid >> 1)*64;
    const int wc = (wid & 1)*64;

    f32x4 acc[4][4];
    #pragma unroll
    for (int m = 0; m < 4; ++m)
        #pragma unroll
        for (int n = 0; n < 4; ++n) acc[m][n] = (f32x4){0.f,0.f,0.f,0.f};

    for (int kt = 0; kt < DIM_/32; ++kt) {
        __syncthreads();
        #pragma unroll
        for (int t = 0; t < 4; ++t) {
            int chunk = t*4 + wid;
            int tile  = chunk >> 3;
            int crow  = (chunk & 7) * 16;
            int grow  = (tile ? col0 : row0) + crow + (lane >> 2);
            const unsigned short* gsrc = (tile ? wb : xb)
                + (size_t)grow*DIM_ + kt*32 + (lane & 3)*8;
            __builtin_amdgcn_global_load_lds(
                (const __attribute__((address_space(1))) void*)gsrc,
                (__attribute__((address_space(3))) void*)(sAB + chunk*512),
                16, 0, 0);
        }
        __syncthreads();

        bf16x8 a[4], b[4];
        #pragma unroll
        for (int m = 0; m < 4; ++m)
            a[m] = *reinterpret_cast<const bf16x8*>(
                sAB + ((wr + m*16 + (lane & 15))*32 + (lane >> 4)*8));
        #pragma unroll
        for (int n = 0; n < 4; ++n)
            b[n] = *reinterpret_cast<const bf16x8*>(
                sAB + 128*32 + ((wc + n*16 + (lane & 15))*32 + (lane >> 4)*8));
        #pragma unroll
        for (int m = 0; m < 4; ++m)
            #pragma unroll
            for (int n = 0; n < 4; ++n)
                acc[m][n] = __builtin_amdgcn_mfma_f32_16x16x32_bf16(
                    a[m], b[n], acc[m][n], 0, 0, 0);
    }

    unsigned short* qa = (unsigned short*)(ws + OFF_QA);
    unsigned short* ka = (unsigned short*)(ws + OFF_KA);
    unsigned short* vt = (unsigned short*)(ws + OFF_VT);
    float* praw = ws + OFF_PRAW;
    const float ss = 0.08838834764831845f;   // (2*64)^-0.5

    #pragma unroll
    for (int n = 0; n < 4; ++n) {
        int o = col0 + wc + n*16 + (lane & 15);
        if (o >= NPROJ) continue;
        #pragma unroll
        for (int m = 0; m < 4; ++m) {
            #pragma unroll
            for (int j = 0; j < 4; ++j) {
                int r = row0 + wr + m*16 + (lane >> 4)*4 + j;
                int bb = r >> 10, nn = r & (N_-1);
                float v = acc[m][n][j];
                if (o < 512) {
                    int h = o >> 6, c = o & 63;
                    qa[((size_t)(bb*H_ + h)*N_ + nn)*96 + c] = f2bf(v*ss);
                } else if (o < 1024) {
                    int oo = o - 512; int h = oo >> 6, c = oo & 63;
                    ka[((size_t)(bb*H_ + h)*N_ + nn)*96 + c] = f2bf(v);
                } else if (o < 1536) {
                    int oo = o - 1024; int h = oo >> 6, c = oo & 63;
                    vt[((size_t)(bb*H_ + h)*80 + c)*N_ + nn] = f2bf(v);
                } else {
                    praw[(size_t)r*288 + (o - 1536)] = v;
                }
            }
        }
    }
}

// ---------------------------------------------------------------------------
// K2: rotate points, q2/k2, write Qa/Ka tails + Vt point rows (+ zero pads)
// ---------------------------------------------------------------------------
__global__ __launch_bounds__(128) void k_prep(
    const float* __restrict__ rot_g,
    const float* __restrict__ trans_g,
    const float* __restrict__ pw_g,
    float* __restrict__ ws)
{
    __shared__ float R[9], T[3];
    __shared__ float rot[3][8][4][3];
    __shared__ float p2[2][8][4];
    __shared__ float q2t[8], k2t[8], coefs[8];
    const int tid = threadIdx.x;
    const int row = blockIdx.x;
    const int b = row >> 10, n = row & (N_-1);

    if (tid < 9)  R[tid] = rot_g[(size_t)row*9 + tid];
    if (tid >= 9 && tid < 12) T[tid-9] = trans_g[(size_t)row*3 + (tid-9)];
    if (tid >= 16 && tid < 24) {
        float pw = pw_g[tid-16];
        coefs[tid-16] = 0.5f * log1pf(__expf(pw)) * (1.0f/6.0f);
    }
    __syncthreads();
    if (tid < 96) {
        int which = tid >> 5, idx = tid & 31;
        int h = idx >> 2, pd = idx & 3;
        const float* p = ws + OFF_PRAW + (size_t)row*288 + which*96 + h*12 + pd*3;
        float px = p[0], py = p[1], pz = p[2];
        float c0 = R[0]*px + R[1]*py + R[2]*pz + T[0];
        float c1 = R[3]*px + R[4]*py + R[5]*pz + T[1];
        float c2 = R[6]*px + R[7]*py + R[8]*pz + T[2];
        rot[which][h][pd][0] = c0;
        rot[which][h][pd][1] = c1;
        rot[which][h][pd][2] = c2;
        if (which < 2) p2[which][h][pd] = c0*c0 + c1*c1 + c2*c2;
    }
    __syncthreads();
    if (tid < 16) {
        int w = tid >> 3, h = tid & 7;
        float s = p2[w][h][0] + p2[w][h][1] + p2[w][h][2] + p2[w][h][3];
        if (w) k2t[h] = s; else q2t[h] = s;
    }
    __syncthreads();

    unsigned short* qa = (unsigned short*)(ws + OFF_QA);
    unsigned short* ka = (unsigned short*)(ws + OFF_KA);
    unsigned short* vt = (unsigned short*)(ws + OFF_VT);

    for (int i = tid; i < 256; i += 128) {
        int h = i >> 5, c = i & 31;
        float qv, kv;
        if (c < 12)      { qv = rot[0][h][c/3][c%3] * 2.f * coefs[h]; kv = rot[1][h][c/3][c%3]; }
        else if (c == 12){ qv = q2t[h];  kv = -coefs[h]; }
        else if (c == 13){ qv = 1.f;     kv = -coefs[h]*k2t[h]; }
        else             { qv = 0.f;     kv = 0.f; }
        size_t base = ((size_t)(b*H_ + h)*N_ + n)*96 + 64 + c;
        qa[base] = f2bf(qv);
        ka[base] = f2bf(kv);
    }
    {
        int h = tid >> 4, r = tid & 15;
        float vv = (r < 12) ? rot[2][h][r/3][r%3] : 0.f;
        vt[((size_t)(b*H_ + h)*80 + 64 + r)*N_ + n] = f2bf(vv);
    }
}

// ---------------------------------------------------------------------------
// K3: MFMA flash attention. grid = 512 blocks, 256 threads.
// ---------------------------------------------------------------------------
#define KPAD 104
#define VPAD 72
__global__ __launch_bounds__(256) void k_attn_mfma(
    const unsigned short* __restrict__ qa_g,
    const unsigned short* __restrict__ ka_g,
    const unsigned short* __restrict__ vt_g,
    float* __restrict__ ws)
{
    __shared__ unsigned short sKa[2][64*KPAD];
    __shared__ unsigned short sVt[2][80*VPAD];
    __shared__ unsigned short sP[4][16*VPAD];
    __shared__ float sMrg[32*80];
    __shared__ float sML[32*2];

    const int tid  = threadIdx.x;
    const int lane = tid & 63;
    const int wid  = tid >> 6;
    const int bh = blockIdx.x >> 5;
    const int qt = blockIdx.x & 31;
    const int q0 = qt * 32;
    const int mrow = (wid & 1) * 16;
    const int half = wid >> 1;
    const int tg   = tid & 127;

    const unsigned short* Qa = qa_g + (size_t)bh*N_*96;
    const unsigned short* Ka = ka_g + (size_t)bh*N_*96;
    const unsigned short* Vt = vt_g + (size_t)bh*80*N_;

    bf16x8 qfr[3];
    {
        int qrow = q0 + mrow + (lane & 15);
        #pragma unroll
        for (int c = 0; c < 3; ++c)
            qfr[c] = *reinterpret_cast<const bf16x8*>(
                Qa + (size_t)qrow*96 + c*32 + (lane >> 4)*8);
    }

    f32x4 acc[5];
    #pragma unroll
    for (int d = 0; d < 5; ++d) acc[d] = (f32x4){0.f,0.f,0.f,0.f};
    float m[4] = {-1e30f,-1e30f,-1e30f,-1e30f};
    float l[4] = {0.f,0.f,0.f,0.f};

    for (int it = 0; it < 8; ++it) {
        const int j0 = (half*8 + it)*64;
        __syncthreads();
        for (int i = tg; i < 768; i += 128) {
            int r = i / 12, c = i % 12;
            *reinterpret_cast<uint4*>(&sKa[half][r*KPAD + c*8]) =
                *reinterpret_cast<const uint4*>(Ka + (size_t)(j0+r)*96 + c*8);
        }
        for (int i = tg; i < 640; i += 128) {
            int r = i >> 3, c = i & 7;
            *reinterpret_cast<uint4*>(&sVt[half][r*VPAD + c*8]) =
                *reinterpret_cast<const uint4*>(Vt + (size_t)r*N_ + j0 + c*8);
        }
        __syncthreads();

        f32x4 s[4];
        #pragma unroll
        for (int t = 0; t < 4; ++t) s[t] = (f32x4){0.f,0.f,0.f,0.f};
        #pragma unroll
        for (int c = 0; c < 3; ++c) {
            #pragma unroll
            for (int t = 0; t < 4; ++t) {
                bf16x8 kb = *reinterpret_cast<const bf16x8*>(
                    &sKa[half][(t*16 + (lane & 15))*KPAD + c*32 + (lane >> 4)*8]);
                s[t] = __builtin_amdgcn_mfma_f32_16x16x32_bf16(qfr[c], kb, s[t], 0, 0, 0);
            }
        }

        float scl[4];
        #pragma unroll
        for (int r = 0; r < 4; ++r) {
            float v = fmaxf(fmaxf(s[0][r], s[1][r]), fmaxf(s[2][r], s[3][r]));
            v = fmaxf(v, __shfl_xor(v, 1));
            v = fmaxf(v, __shfl_xor(v, 2));
            v = fmaxf(v, __shfl_xor(v, 4));
            v = fmaxf(v, __shfl_xor(v, 8));
            float mn = fmaxf(m[r], v);
            scl[r] = __expf(m[r] - mn);
            m[r] = mn;
        }
        float ps[4] = {0.f,0.f,0.f,0.f};
        #pragma unroll
        for (int t = 0; t < 4; ++t) {
            #pragma unroll
            for (int r = 0; r < 4; ++r) {
                float p = __expf(s[t][r] - m[r]);
                ps[r] += p;
                sP[wid][((lane >> 4)*4 + r)*VPAD + t*16 + (lane & 15)] = f2bf(p);
            }
        }
        #pragma unroll
        for (int r = 0; r < 4; ++r) {
            float v = ps[r];
            v += __shfl_xor(v, 1);
            v += __shfl_xor(v, 2);
            v += __shfl_xor(v, 4);
            v += __shfl_xor(v, 8);
            l[r] = l[r]*scl[r] + v;
        }
        #pragma unroll
        for (int d = 0; d < 5; ++d)
            #pragma unroll
            for (int r = 0; r < 4; ++r) acc[d][r] *= scl[r];

        #pragma unroll
        for (int kk = 0; kk < 2; ++kk) {
            bf16x8 pa = *reinterpret_cast<const bf16x8*>(
                &sP[wid][(lane & 15)*VPAD + kk*32 + (lane >> 4)*8]);
            #pragma unroll
            for (int dt = 0; dt < 5; ++dt) {
                bf16x8 vb = *reinterpret_cast<const bf16x8*>(
                    &sVt[half][(dt*16 + (lane & 15))*VPAD + kk*32 + (lane >> 4)*8]);
                acc[dt] = __builtin_amdgcn_mfma_f32_16x16x32_bf16(pa, vb, acc[dt], 0, 0, 0);
            }
        }
    }

    __syncthreads();
    if (half == 1) {
        #pragma unroll
        for (int r = 0; r < 4; ++r) {
            int rl = mrow + (lane >> 4)*4 + r;
            #pragma unroll
            for (int dt = 0; dt < 5; ++dt)
                sMrg[rl*80 + dt*16 + (lane & 15)] = acc[dt][r];
            if ((lane & 15) == 0) { sML[rl*2] = m[r]; sML[rl*2+1] = l[r]; }
        }
    }
    __syncthreads();
    if (half == 0) {
        float* ws_rs = ws + OFF_RS + (size_t)bh*N_*DH_;
        float* ws_rp = ws + OFF_RP + (size_t)bh*N_*12;
        #pragma unroll
        for (int r = 0; r < 4; ++r) {
            int rl = mrow + (lane >> 4)*4 + r;
            float m2 = sML[rl*2], l2 = sML[rl*2+1];
            float mm = fmaxf(m[r], m2);
            float f1 = __expf(m[r] - mm), f2 = __expf(m2 - mm);
            float inv = 1.f / (l[r]*f1 + l2*f2);
            int i = q0 + rl;
            #pragma unroll
            for (int dt = 0; dt < 5; ++dt) {
                float val = (acc[dt][r]*f1 + sMrg[rl*80 + dt*16 + (lane & 15)]*f2) * inv;
                int d = dt*16 + (lane & 15);
                if (d < 64)
                    ws_rs[(size_t)i*DH_ + d] = val;
                else if (d - 64 < 12)
                    ws_rp[(size_t)i*12 + (d - 64)] = val;
            }
        }
    }
}

// ---------------------------------------------------------------------------
// K4a: finalize features -> fb[2048][640] bf16. grid = 256, block = 256.
// ---------------------------------------------------------------------------
__global__ __launch_bounds__(256) void k_fin_prep(
    const float* __restrict__ rotations,
    const float* __restrict__ translations,
    const float* __restrict__ ws,
    unsigned short* __restrict__ fb)
{
    __shared__ float sF[8][FDIM];
    const int tid = threadIdx.x;
    const int row0 = blockIdx.x * 8;
    const int b = row0 >> 10;
    const float* ws_rs = ws + OFF_RS;
    const float* ws_rp = ws + OFF_RP;

    for (int i = tid; i < 8*512; i += 256) {
        int r = i >> 9, f = i & 511;
        int h = f >> 6, c = f & 63;
        int n = (row0 & (N_-1)) + r;
        sF[r][f] = ws_rs[(((size_t)(b*H_ + h))*N_ + n)*DH_ + c];
    }
    {
        int r = tid >> 5;
        int idx = tid & 31;
        int h = idx >> 2, pd = idx & 3;
        int row = row0 + r;
        int n = row & (N_-1);
        const float* rp = ws_rp + (((size_t)(b*H_ + h))*N_ + n)*12 + pd*3;
        const float* R = rotations + (size_t)row*9;
        const float* T = translations + (size_t)row*3;
        float d0 = rp[0] - T[0], d1 = rp[1] - T[1], d2 = rp[2] - T[2];
        float l0 = R[0]*d0 + R[3]*d1 + R[6]*d2;
        float l1 = R[1]*d0 + R[4]*d1 + R[7]*d2;
        float l2 = R[2]*d0 + R[5]*d1 + R[8]*d2;
        sF[r][512 + h*12 + pd*3 + 0] = l0;
        sF[r][512 + h*12 + pd*3 + 1] = l1;
        sF[r][512 + h*12 + pd*3 + 2] = l2;
        sF[r][608 + h*4 + pd] = sqrtf(l0*l0 + l1*l1 + l2*l2 + 1e-8f);
    }
    __syncthreads();

    #pragma unroll
    for (int r = 0; r < 8; ++r) {
        for (int f = tid; f < FDIM; f += 256) {
            fb[(size_t)(row0 + r)*FDIM + f] = f2bf(sF[r][f]);
        }
    }
}

// ---------------------------------------------------------------------------
// K4b: output GEMM via MFMA. out[2048][768] = fb[2048][640] . wob[768][640]^T + bout
// grid = 16 x 6 = 96 blocks, 256 threads.
// ---------------------------------------------------------------------------
__global__ __launch_bounds__(256) void k_out_mfma(
    const unsigned short* __restrict__ fb,
    const unsigned short* __restrict__ wob,
    const float* __restrict__ bout,
    float* __restrict__ out)
{
    __shared__ unsigned short sAB[2*128*32];
    const int tid  = threadIdx.x;
    const int lane = tid & 63;
    const int wid  = tid >> 6;
    const int mt = blockIdx.x & 15;
    const int nt = blockIdx.x >> 4;
    const int row0 = mt*128;
    const int col0 = nt*128;
    const int wr = (wid >> 1)*64;
    const int wc = (wid & 1)*64;

    f32x4 acc[4][4];
    #pragma unroll
    for (int m = 0; m < 4; ++m)
        #pragma unroll
        for (int n = 0; n < 4; ++n) acc[m][n] = (f32x4){0.f,0.f,0.f,0.f};

    for (int kt = 0; kt < FDIM/32; ++kt) {
        __syncthreads();
        #pragma unroll
        for (int t = 0; t < 4; ++t) {
            int chunk = t*4 + wid;
            int tile  = chunk >> 3;
            int crow  = (chunk & 7) * 16;
            int grow  = (tile ? col0 : row0) + crow + (lane >> 2);
            const unsigned short* gsrc = (tile ? wob : fb)
                + (size_t)grow*FDIM + kt*32 + (lane & 3)*8;
            __builtin_amdgcn_global_load_lds(
                (const __attribute__((address_space(1))) void*)gsrc,
                (__attribute__((address_space(3))) void*)(sAB + chunk*512),
                16, 0, 0);
        }
        __syncthreads();

        bf16x8 a[4], b[4];
        #pragma unroll
        for (int m = 0; m < 4; ++m)
            a[m] = *reinterpret_cast<const bf16x8*>(
                sAB + ((wr + m*16 + (lane & 15))*32 + (lane >> 4)*8));
        #pragma unroll
        for (int n = 0; n < 4; ++n)
            b[n] = *reinterpret_cast<const bf16x8*>(
                sAB + 128*32 + ((wc + n*16 + (lane & 15))*32 + (lane >> 4)*8));
        #pragma unroll
        for (int m = 0; m < 4; ++m)
            #pragma unroll
            for (int n = 0; n < 4; ++n)
                acc[m][n] = __builtin_amdgcn_mfma_f32_16x16x32_bf16(
                    a[m], b[n], acc[m][n], 0, 0, 0);
    }

    #pragma unroll
    for (int n = 0; n < 4; ++n) {
        int o = col0 + wc + n*16 + (lane & 15);
        float bo = bout[o];
        #pragma unroll
        for (int m = 0; m < 4; ++m) {
            #pragma unroll
            for (int j = 0; j < 4; ++j) {
                int r = row0 + wr + m*16 + (lane >> 4)*4 + j;
                out[(size_t)r*DIM_ + o] = acc[m][n][j] + bo;
            }
        }
    }
}

// ---------------------------------------------------------------------------
extern "C" void kernel_launch(void* const* d_in, const int* in_sizes, int n_in,
                              void* d_out, int out_size, void* d_ws, size_t ws_size,
                              hipStream_t stream) {
    const float* x            = (const float*)d_in[0];
    const float* rotations    = (const float*)d_in[1];
    const float* translations = (const float*)d_in[2];
    const float* Wsq          = (const float*)d_in[3];
    const float* Wsk          = (const float*)d_in[4];
    const float* Wsv          = (const float*)d_in[5];
    const float* Wpq          = (const float*)d_in[6];
    const float* Wpk          = (const float*)d_in[7];
    const float* Wpv          = (const float*)d_in[8];
    const float* pweights     = (const float*)d_in[9];
    const float* Wout         = (const float*)d_in[10];
    const float* bout         = (const float*)d_in[11];
    float* out = (float*)d_out;
    float* ws  = (float*)d_ws;

    unsigned short* xb  = (unsigned short*)(ws + OFF_XB);
    unsigned short* wb  = (unsigned short*)(ws + OFF_WB);
    unsigned short* qa  = (unsigned short*)(ws + OFF_QA);
    unsigned short* ka  = (unsigned short*)(ws + OFF_KA);
    unsigned short* vt  = (unsigned short*)(ws + OFF_VT);
    unsigned short* fb  = (unsigned short*)(ws + OFF_FB);
    unsigned short* wob = (unsigned short*)(ws + OFF_WOB);

    k_cvt_x<<<(B_*N_*DIM_/4 + 255)/256, 256, 0, stream>>>(x, xb);
    k_cvt_w<<<(NPAD*DIM_/4 + 255)/256, 256, 0, stream>>>(Wsq, Wsk, Wsv, Wpq, Wpk, Wpv, wb);
    k_proj_mfma<<<16*15, 256, 0, stream>>>(xb, wb, ws);
    k_prep<<<B_*N_, 128, 0, stream>>>(rotations, translations, pweights, ws);
    k_attn_mfma<<<BH_*32, 256, 0, stream>>>(qa, ka, vt, ws);
    // wob overwrites wb region: safe, k_proj_mfma has consumed it (stream order)
    k_cvt_wout<<<(DIM_*FDIM/4 + 255)/256, 256, 0, stream>>>(Wout, wob);
    k_fin_prep<<<B_*N_/8, 256, 0, stream>>>(rotations, translations, ws, fb);
    k_out_mfma<<<16*6, 256, 0, stream>>>(fb, wob, bout, out);
}